// Round 5
// baseline (320.398 us; speedup 1.0000x reference)
//
#include <hip/hip_runtime.h>
#include <math.h>

#define NN 32768
#define EN 1048576

// C = 1/sqrt(E[gelu(z)^2]) , E = 1/3 + 1/(2*pi*sqrt(3))
#define C_GELU_F 1.5335262f

// ---------------- histogram of receivers (cnt zeroed by memset) -------------
__global__ __launch_bounds__(256) void hist_k(const int* __restrict__ rcv,
                                              int* __restrict__ cnt) {
    int i = blockIdx.x * 256 + threadIdx.x;
    int4 r = ((const int4*)rcv)[i];
    atomicAdd(&cnt[r.x], 1);
    atomicAdd(&cnt[r.y], 1);
    atomicAdd(&cnt[r.z], 1);
    atomicAdd(&cnt[r.w], 1);
}

// ---------------- exclusive scan of 32K counts -> row_ptr -------------------
__global__ __launch_bounds__(1024) void scan_k(const int* __restrict__ cnt,
                                               int* __restrict__ row_ptr) {
    __shared__ unsigned part[1024];
    int t = threadIdx.x;
    unsigned loc[32];
    const int4* c4 = (const int4*)(cnt + t * 32);
    unsigned run = 0;
#pragma unroll
    for (int q = 0; q < 8; ++q) {
        int4 v = c4[q];
        loc[4*q+0] = run; run += (unsigned)v.x;
        loc[4*q+1] = run; run += (unsigned)v.y;
        loc[4*q+2] = run; run += (unsigned)v.z;
        loc[4*q+3] = run; run += (unsigned)v.w;
    }
    part[t] = run;
    __syncthreads();
    for (int d = 1; d < 1024; d <<= 1) {
        unsigned v = (t >= d) ? part[t - d] : 0u;
        __syncthreads();
        part[t] += v;
        __syncthreads();
    }
    unsigned base = part[t] - run;
    int4* rp4 = (int4*)(row_ptr + t * 32);
#pragma unroll
    for (int q = 0; q < 8; ++q) {
        int4 o;
        o.x = (int)(base + loc[4*q+0]);
        o.y = (int)(base + loc[4*q+1]);
        o.z = (int)(base + loc[4*q+2]);
        o.w = (int)(base + loc[4*q+3]);
        rp4[q] = o;
    }
    if (t == 1023) row_ptr[NN] = (int)part[1023];
}

// ---------------- pack positions into float4 --------------------------------
__global__ __launch_bounds__(256) void pos_k(const float* __restrict__ pos,
                                             float4* __restrict__ posw) {
    int n = blockIdx.x * 256 + threadIdx.x;
    posw[n] = make_float4(pos[3*n], pos[3*n+1], pos[3*n+2], 0.f);
}

// ---------------- CSR fill: packed edge record {sender_pos, sender_id} ------
__global__ __launch_bounds__(256) void fill_k(const int* __restrict__ snd,
                                              const int* __restrict__ rcv,
                                              const int* __restrict__ row_ptr,
                                              int* __restrict__ cur,
                                              const float4* __restrict__ posw,
                                              float4* __restrict__ edata) {
    int e = blockIdx.x * 256 + threadIdx.x;
    int r = rcv[e], s = snd[e];
    int p = atomicAdd(&cur[r], 1);
    float4 sp = posw[s];
    sp.w = __int_as_float(s);
    edata[row_ptr[r] + p] = sp;
}

// ---------------- fused aggregate + node update ------------------------------
// Per 16-lane node group, chunk of 16 edges:
//   step A: lane e computes SH for edge e (from packed record, no extra load),
//           stores TRANSPOSED yT[comp][e] + sender ids into LDS (zero-masked
//           tail -> branchless step B).
//   step B: lane j reads its row yT[j][0..15] (4x b128) + senders (4x b128
//           broadcast) -> 16 edges x (4 indep global dwordx4 + 16 FMA),
//           zero per-edge DS ops.
// LDS is a UNION: sY region is reused for the weight tiles after the edge
// loop (44 KB -> 3 blocks/CU; launch_bounds(512,6) caps VGPR at 85 so
// 6 waves/SIMD fit).
#define GROUPS 32
#define BLK 512
#define GST 344            // floats/group: 16 rows x 20 + 16 senders + 8 pad

__global__ __launch_bounds__(512, 6) void fused_k(const float* __restrict__ x,
                                                  const float4* __restrict__ posw,
                                                  const int* __restrict__ row_ptr,
                                                  const float4* __restrict__ edata,
                                                  const float* __restrict__ Wpre,
                                                  const float* __restrict__ Wpost,
                                                  const float* __restrict__ Wsc,
                                                  float* __restrict__ out) {
    __shared__ float sU[GROUPS * GST];   // 44032 B

    int t = threadIdx.x;
    int g = t >> 4;
    int j = t & 15;
    int n = blockIdx.x * GROUPS + g;
    int beg = row_ptr[n], end = row_ptr[n + 1];
    int cnt = end - beg;
    float4 rp = posw[n];
    float* yg = sU + g * GST;            // yT rows at m*20, senders at 320

    const float s3   = 1.7320508075688772f;
    const float s5   = 2.2360679774997896f;
    const float s15  = 3.8729833462074170f;
    const float s7   = 2.6457513110645907f;
    const float s105 = 10.246950765959598f;
    const float s35_8 = 2.0916500663351889f;
    const float s21_8 = 1.6201851746019651f;

    float acc[16];
#pragma unroll
    for (int u = 0; u < 16; ++u) acc[u] = 0.f;

    int nch = (cnt + 15) >> 4;
    for (int c = 0; c < nch; ++c) {
        // ---- step A: my edge's SH (transposed store, zero-masked tail) ----
        int k = (c << 4) + j;
        bool valid = k < cnt;
        int ki = valid ? k : cnt - 1;
        float4 rec = edata[beg + ki];
        int sE = __float_as_int(rec.w);
        float vx = rp.x - rec.x, vy = rp.y - rec.y, vz = rp.z - rec.z;
        float n2 = vx*vx + vy*vy + vz*vz;
        float inv;
        if (valid && n2 > 0.f) {
            inv = rsqrtf(n2);
            inv = inv * (1.5f - 0.5f * n2 * inv * inv);   // Newton: ~exact f32
        } else inv = 0.f;
        float X = vx*inv, Y = vy*inv, Z = vz*inv;
        float XX = X*X, YY = Y*Y, ZZ = Z*Z;
        float zm = valid ? 1.f : 0.f;

        yg[ 0*20 + j] = zm;                              // l=0 (masked)
        yg[ 1*20 + j] = s3*X;
        yg[ 2*20 + j] = s3*Y;
        yg[ 3*20 + j] = s3*Z;
        yg[ 4*20 + j] = s15*X*Y;
        yg[ 5*20 + j] = s15*Y*Z;
        yg[ 6*20 + j] = zm * (0.5f*s5*(3.f*ZZ - 1.f));   // masked (const term)
        yg[ 7*20 + j] = s15*X*Z;
        yg[ 8*20 + j] = 0.5f*s15*(XX - YY);
        yg[ 9*20 + j] = s35_8*Y*(3.f*XX - YY);
        yg[10*20 + j] = s105*X*Y*Z;
        yg[11*20 + j] = s21_8*Y*(5.f*ZZ - 1.f);
        yg[12*20 + j] = 0.5f*s7*Z*(5.f*ZZ - 3.f);
        yg[13*20 + j] = s21_8*X*(5.f*ZZ - 1.f);
        yg[14*20 + j] = 0.5f*s105*Z*(XX - YY);
        yg[15*20 + j] = s35_8*X*(XX - 3.f*YY);
        ((int*)(yg + 320))[j] = sE;

        // ---- step B: my j-column over the chunk's 16 edges ----
        const float4* yp = (const float4*)(yg + j * 20);  // row j: y_e[j], e=0..15
        float4 yv0 = yp[0], yv1 = yp[1], yv2 = yp[2], yv3 = yp[3];
        const int4* sip = (const int4*)(yg + 320);        // broadcast reads
        int4 sa0 = sip[0], sa1 = sip[1], sa2 = sip[2], sa3 = sip[3];
        float yarr[16] = { yv0.x, yv0.y, yv0.z, yv0.w,
                           yv1.x, yv1.y, yv1.z, yv1.w,
                           yv2.x, yv2.y, yv2.z, yv2.w,
                           yv3.x, yv3.y, yv3.z, yv3.w };
        int sarr[16] = { sa0.x, sa0.y, sa0.z, sa0.w,
                         sa1.x, sa1.y, sa1.z, sa1.w,
                         sa2.x, sa2.y, sa2.z, sa2.w,
                         sa3.x, sa3.y, sa3.z, sa3.w };
#pragma unroll
        for (int e = 0; e < 16; ++e) {
            float y = yarr[e];
            const float4* xp = (const float4*)(x + (sarr[e] << 4));
            float4 a0 = xp[0], a1 = xp[1], a2 = xp[2], a3 = xp[3];
            acc[0]  += a0.x * y;  acc[1]  += a0.y * y;
            acc[2]  += a0.z * y;  acc[3]  += a0.w * y;
            acc[4]  += a1.x * y;  acc[5]  += a1.y * y;
            acc[6]  += a1.z * y;  acc[7]  += a1.w * y;
            acc[8]  += a2.x * y;  acc[9]  += a2.y * y;
            acc[10] += a2.z * y;  acc[11] += a2.w * y;
            acc[12] += a3.x * y;  acc[13] += a3.y * y;
            acc[14] += a3.z * y;  acc[15] += a3.w * y;
        }
    }

    // ---- stage weights into the SAME LDS region (sY is dead now) ----
    __syncthreads();
    float* sPre  = sU;            // 4 x 516
    float* sPost = sU + 2064;     // 4 x 1028
    float* sSc   = sU + 6176;     // 512
    for (int idx = t; idx < 2048; idx += BLK)
        sPre[(idx >> 9)*516 + (idx & 511)] = Wpre[idx];
    for (int idx = t; idx < 4096; idx += BLK)
        sPost[(idx >> 10)*1028 + (idx & 1023)] = Wpost[idx];
    sSc[t] = Wsc[t];
    __syncthreads();

    // ---- phase 3: per-(n,j) node update; input = acc registers ----
    int l, i, offl, deg;
    if (j == 0)      { l = 0; i = 0;     offl = 0;   deg = 1; }
    else if (j < 4)  { l = 1; i = j - 1; offl = 32;  deg = 3; }
    else if (j < 9)  { l = 2; i = j - 4; offl = 128; deg = 5; }
    else             { l = 3; i = j - 9; offl = 288; deg = 7; }

    const float c1 = 0.0078125f;            // (1/DENOM) * inv_in
    const float c2 = 0.17677669529663687f;  // 1/sqrt(32)

    float p[32];
#pragma unroll
    for (int v = 0; v < 32; ++v) p[v] = 0.f;
    const float* wp = sPre + l * 516;
#pragma unroll
    for (int uu = 0; uu < 16; ++uu) {
        float a = acc[uu];
        const float4* w4 = (const float4*)(wp + (uu << 5));
#pragma unroll
        for (int vq = 0; vq < 8; ++vq) {
            float4 w = w4[vq];
            p[4*vq+0] += a * w.x;
            p[4*vq+1] += a * w.y;
            p[4*vq+2] += a * w.z;
            p[4*vq+3] += a * w.w;
        }
    }
#pragma unroll
    for (int v = 0; v < 32; ++v) p[v] *= c1;

    if (j == 0) {
#pragma unroll
        for (int v = 0; v < 32; ++v) {
            float pv = p[v];
            p[v] = C_GELU_F * 0.5f * pv * (1.f + erff(pv * 0.7071067811865476f));
        }
    }

    float q[32];
#pragma unroll
    for (int w = 0; w < 32; ++w) q[w] = 0.f;
    const float* wq = sPost + l * 1028;
#pragma unroll
    for (int v = 0; v < 32; ++v) {
        float pv = p[v];
        const float4* w4 = (const float4*)(wq + (v << 5));
#pragma unroll
        for (int wd = 0; wd < 8; ++wd) {
            float4 w = w4[wd];
            q[4*wd+0] += pv * w.x;
            q[4*wd+1] += pv * w.y;
            q[4*wd+2] += pv * w.z;
            q[4*wd+3] += pv * w.w;
        }
    }
#pragma unroll
    for (int w = 0; w < 32; ++w) q[w] *= c2;

    if (j == 0) {   // shortcut: (x @ Wsc) * 1/4, only the 0e path
        const float* xp = x + (n << 4);
#pragma unroll
        for (int uu = 0; uu < 16; ++uu) {
            float xv = 0.25f * xp[uu];
            const float4* w4 = (const float4*)(sSc + (uu << 5));
#pragma unroll
            for (int wd = 0; wd < 8; ++wd) {
                float4 w = w4[wd];
                q[4*wd+0] += xv * w.x;
                q[4*wd+1] += xv * w.y;
                q[4*wd+2] += xv * w.z;
                q[4*wd+3] += xv * w.w;
            }
        }
    }

    float* op = out + (n << 9) + offl + i;
#pragma unroll
    for (int w = 0; w < 32; ++w) op[w * deg] = q[w];
}

extern "C" void kernel_launch(void* const* d_in, const int* in_sizes, int n_in,
                              void* d_out, int out_size, void* d_ws, size_t ws_size,
                              hipStream_t stream) {
    const float* x     = (const float*)d_in[0];
    const float* pos   = (const float*)d_in[1];
    const float* Wpre  = (const float*)d_in[2];
    const float* Wpost = (const float*)d_in[3];
    const float* Wsc   = (const float*)d_in[4];
    const int*   snd   = (const int*)d_in[5];
    const int*   rcv   = (const int*)d_in[6];
    float* out = (float*)d_out;

    char* ws = (char*)d_ws;
    int*    cnt     = (int*)(ws);                 // 128 KiB
    int*    cur     = (int*)(ws + 0x20000);       // 128 KiB
    int*    row_ptr = (int*)(ws + 0x40000);       // 128 KiB + 4
    float4* posw    = (float4*)(ws + 0x60040);    // 512 KiB (16B aligned)
    float4* edata   = (float4*)(ws + 0xE0040);    // 16 MiB (16B aligned)

    hipMemsetAsync(ws, 0, 0x40000, stream);       // cnt + cur
    hist_k<<<EN / 1024, 256, 0, stream>>>(rcv, cnt);
    scan_k<<<1, 1024, 0, stream>>>(cnt, row_ptr);
    pos_k<<<NN / 256, 256, 0, stream>>>(pos, posw);
    fill_k<<<EN / 256, 256, 0, stream>>>(snd, rcv, row_ptr, cur, posw, edata);
    fused_k<<<NN / GROUPS, BLK, 0, stream>>>(x, posw, row_ptr, edata,
                                             Wpre, Wpost, Wsc, out);
}

// Round 6
// 278.356 us; speedup vs baseline: 1.1510x; 1.1510x over previous
//
#include <hip/hip_runtime.h>
#include <math.h>

#define NN 32768
#define EN 1048576

// C = 1/sqrt(E[gelu(z)^2]) , E = 1/3 + 1/(2*pi*sqrt(3))
#define C_GELU_F 1.5335262f

// ---------------- histogram of receivers (cnt zeroed by memset) -------------
__global__ __launch_bounds__(256) void hist_k(const int* __restrict__ rcv,
                                              int* __restrict__ cnt) {
    int i = blockIdx.x * 256 + threadIdx.x;
    int4 r = ((const int4*)rcv)[i];
    atomicAdd(&cnt[r.x], 1);
    atomicAdd(&cnt[r.y], 1);
    atomicAdd(&cnt[r.z], 1);
    atomicAdd(&cnt[r.w], 1);
}

// ---------------- exclusive scan of 32K counts -> row_ptr -------------------
__global__ __launch_bounds__(1024) void scan_k(const int* __restrict__ cnt,
                                               int* __restrict__ row_ptr) {
    __shared__ unsigned part[1024];
    int t = threadIdx.x;
    unsigned loc[32];
    const int4* c4 = (const int4*)(cnt + t * 32);
    unsigned run = 0;
#pragma unroll
    for (int q = 0; q < 8; ++q) {
        int4 v = c4[q];
        loc[4*q+0] = run; run += (unsigned)v.x;
        loc[4*q+1] = run; run += (unsigned)v.y;
        loc[4*q+2] = run; run += (unsigned)v.z;
        loc[4*q+3] = run; run += (unsigned)v.w;
    }
    part[t] = run;
    __syncthreads();
    for (int d = 1; d < 1024; d <<= 1) {
        unsigned v = (t >= d) ? part[t - d] : 0u;
        __syncthreads();
        part[t] += v;
        __syncthreads();
    }
    unsigned base = part[t] - run;
    int4* rp4 = (int4*)(row_ptr + t * 32);
#pragma unroll
    for (int q = 0; q < 8; ++q) {
        int4 o;
        o.x = (int)(base + loc[4*q+0]);
        o.y = (int)(base + loc[4*q+1]);
        o.z = (int)(base + loc[4*q+2]);
        o.w = (int)(base + loc[4*q+3]);
        rp4[q] = o;
    }
    if (t == 1023) row_ptr[NN] = (int)part[1023];
}

// ---------------- CSR fill: packed edge record {sender_pos, sender_id} ------
__global__ __launch_bounds__(256) void fill_k(const int* __restrict__ snd,
                                              const int* __restrict__ rcv,
                                              const int* __restrict__ row_ptr,
                                              int* __restrict__ cur,
                                              const float* __restrict__ pos,
                                              float4* __restrict__ edata) {
    int e = blockIdx.x * 256 + threadIdx.x;
    int r = rcv[e], s = snd[e];
    int p = atomicAdd(&cur[r], 1);
    const float* ps = pos + 3 * s;
    float4 rec = make_float4(ps[0], ps[1], ps[2], __int_as_float(s));
    edata[row_ptr[r] + p] = rec;
}

// ---------------- fused aggregate + node update ------------------------------
// Per 16-lane node group, chunk of 16 edges:
//   step A: lane e computes SH for edge e (from packed record), stores
//           TRANSPOSED yT[comp][e] + sender ids into LDS (zero-masked tail).
//   step B: lane j reads row yT[j][0..15] (4x b128) + senders (4x b128
//           broadcast) -> 16 edges x (4 indep global dwordx4, L1-hit heavy,
//           + 16 FMA). Zero per-edge DS ops.
// LDS UNION: sY region reused for weight tiles after the edge loop
// (44 KB -> 3 blocks/CU). launch_bounds(512,4): VGPR cap 128 — the (512,6)
// cap of 85 caused scratch spills (R5: VGPR 40, +25MB FETCH/WRITE, 152us).
#define GROUPS 32
#define BLK 512
#define GST 344            // floats/group: 16 rows x 20 + 16 senders + 8 pad

__global__ __launch_bounds__(512, 4) void fused_k(const float* __restrict__ x,
                                                  const float* __restrict__ pos,
                                                  const int* __restrict__ row_ptr,
                                                  const float4* __restrict__ edata,
                                                  const float* __restrict__ Wpre,
                                                  const float* __restrict__ Wpost,
                                                  const float* __restrict__ Wsc,
                                                  float* __restrict__ out) {
    __shared__ float sU[GROUPS * GST];   // 44032 B

    int t = threadIdx.x;
    int g = t >> 4;
    int j = t & 15;
    int n = blockIdx.x * GROUPS + g;
    int beg = row_ptr[n], end = row_ptr[n + 1];
    int cnt = end - beg;
    const float* pr = pos + 3 * n;       // L2-hit, group-broadcast
    float rpx = pr[0], rpy = pr[1], rpz = pr[2];
    float* yg = sU + g * GST;            // yT rows at m*20, senders at 320

    const float s3   = 1.7320508075688772f;
    const float s5   = 2.2360679774997896f;
    const float s15  = 3.8729833462074170f;
    const float s7   = 2.6457513110645907f;
    const float s105 = 10.246950765959598f;
    const float s35_8 = 2.0916500663351889f;
    const float s21_8 = 1.6201851746019651f;

    float acc[16];
#pragma unroll
    for (int u = 0; u < 16; ++u) acc[u] = 0.f;

    int nch = (cnt + 15) >> 4;
    for (int c = 0; c < nch; ++c) {
        // ---- step A: my edge's SH (transposed store, zero-masked tail) ----
        int k = (c << 4) + j;
        bool valid = k < cnt;
        int ki = valid ? k : cnt - 1;
        float4 rec = edata[beg + ki];
        int sE = __float_as_int(rec.w);
        float vx = rpx - rec.x, vy = rpy - rec.y, vz = rpz - rec.z;
        float n2 = vx*vx + vy*vy + vz*vz;
        float inv;
        if (valid && n2 > 0.f) {
            inv = rsqrtf(n2);
            inv = inv * (1.5f - 0.5f * n2 * inv * inv);   // Newton: ~exact f32
        } else inv = 0.f;
        float X = vx*inv, Y = vy*inv, Z = vz*inv;
        float XX = X*X, YY = Y*Y, ZZ = Z*Z;
        float zm = valid ? 1.f : 0.f;

        yg[ 0*20 + j] = zm;                              // l=0 (masked)
        yg[ 1*20 + j] = s3*X;
        yg[ 2*20 + j] = s3*Y;
        yg[ 3*20 + j] = s3*Z;
        yg[ 4*20 + j] = s15*X*Y;
        yg[ 5*20 + j] = s15*Y*Z;
        yg[ 6*20 + j] = zm * (0.5f*s5*(3.f*ZZ - 1.f));   // masked (const term)
        yg[ 7*20 + j] = s15*X*Z;
        yg[ 8*20 + j] = 0.5f*s15*(XX - YY);
        yg[ 9*20 + j] = s35_8*Y*(3.f*XX - YY);
        yg[10*20 + j] = s105*X*Y*Z;
        yg[11*20 + j] = s21_8*Y*(5.f*ZZ - 1.f);
        yg[12*20 + j] = 0.5f*s7*Z*(5.f*ZZ - 3.f);
        yg[13*20 + j] = s21_8*X*(5.f*ZZ - 1.f);
        yg[14*20 + j] = 0.5f*s105*Z*(XX - YY);
        yg[15*20 + j] = s35_8*X*(XX - 3.f*YY);
        ((int*)(yg + 320))[j] = sE;

        // ---- step B: my j-column over the chunk's 16 edges ----
        const float4* yp = (const float4*)(yg + j * 20);  // row j: y_e[j]
        float4 yv0 = yp[0], yv1 = yp[1], yv2 = yp[2], yv3 = yp[3];
        const int4* sip = (const int4*)(yg + 320);        // broadcast reads
        int4 sa0 = sip[0], sa1 = sip[1], sa2 = sip[2], sa3 = sip[3];
        float yarr[16] = { yv0.x, yv0.y, yv0.z, yv0.w,
                           yv1.x, yv1.y, yv1.z, yv1.w,
                           yv2.x, yv2.y, yv2.z, yv2.w,
                           yv3.x, yv3.y, yv3.z, yv3.w };
        int sarr[16] = { sa0.x, sa0.y, sa0.z, sa0.w,
                         sa1.x, sa1.y, sa1.z, sa1.w,
                         sa2.x, sa2.y, sa2.z, sa2.w,
                         sa3.x, sa3.y, sa3.z, sa3.w };
#pragma unroll
        for (int e = 0; e < 16; ++e) {
            float y = yarr[e];
            const float4* xp = (const float4*)(x + (sarr[e] << 4));
            float4 a0 = xp[0], a1 = xp[1], a2 = xp[2], a3 = xp[3];
            acc[0]  += a0.x * y;  acc[1]  += a0.y * y;
            acc[2]  += a0.z * y;  acc[3]  += a0.w * y;
            acc[4]  += a1.x * y;  acc[5]  += a1.y * y;
            acc[6]  += a1.z * y;  acc[7]  += a1.w * y;
            acc[8]  += a2.x * y;  acc[9]  += a2.y * y;
            acc[10] += a2.z * y;  acc[11] += a2.w * y;
            acc[12] += a3.x * y;  acc[13] += a3.y * y;
            acc[14] += a3.z * y;  acc[15] += a3.w * y;
        }
    }

    // ---- stage weights into the SAME LDS region (sY is dead now) ----
    __syncthreads();
    float* sPre  = sU;            // 4 x 516
    float* sPost = sU + 2064;     // 4 x 1028
    float* sSc   = sU + 6176;     // 512
    for (int idx = t; idx < 2048; idx += BLK)
        sPre[(idx >> 9)*516 + (idx & 511)] = Wpre[idx];
    for (int idx = t; idx < 4096; idx += BLK)
        sPost[(idx >> 10)*1028 + (idx & 1023)] = Wpost[idx];
    sSc[t] = Wsc[t];
    __syncthreads();

    // ---- phase 3: per-(n,j) node update; input = acc registers ----
    int l, i, offl, deg;
    if (j == 0)      { l = 0; i = 0;     offl = 0;   deg = 1; }
    else if (j < 4)  { l = 1; i = j - 1; offl = 32;  deg = 3; }
    else if (j < 9)  { l = 2; i = j - 4; offl = 128; deg = 5; }
    else             { l = 3; i = j - 9; offl = 288; deg = 7; }

    const float c1 = 0.0078125f;            // (1/DENOM) * inv_in
    const float c2 = 0.17677669529663687f;  // 1/sqrt(32)

    float p[32];
#pragma unroll
    for (int v = 0; v < 32; ++v) p[v] = 0.f;
    const float* wp = sPre + l * 516;
#pragma unroll
    for (int uu = 0; uu < 16; ++uu) {
        float a = acc[uu];
        const float4* w4 = (const float4*)(wp + (uu << 5));
#pragma unroll
        for (int vq = 0; vq < 8; ++vq) {
            float4 w = w4[vq];
            p[4*vq+0] += a * w.x;
            p[4*vq+1] += a * w.y;
            p[4*vq+2] += a * w.z;
            p[4*vq+3] += a * w.w;
        }
    }
#pragma unroll
    for (int v = 0; v < 32; ++v) p[v] *= c1;

    if (j == 0) {
#pragma unroll
        for (int v = 0; v < 32; ++v) {
            float pv = p[v];
            p[v] = C_GELU_F * 0.5f * pv * (1.f + erff(pv * 0.7071067811865476f));
        }
    }

    float q[32];
#pragma unroll
    for (int w = 0; w < 32; ++w) q[w] = 0.f;
    const float* wq = sPost + l * 1028;
#pragma unroll
    for (int v = 0; v < 32; ++v) {
        float pv = p[v];
        const float4* w4 = (const float4*)(wq + (v << 5));
#pragma unroll
        for (int wd = 0; wd < 8; ++wd) {
            float4 w = w4[wd];
            q[4*wd+0] += pv * w.x;
            q[4*wd+1] += pv * w.y;
            q[4*wd+2] += pv * w.z;
            q[4*wd+3] += pv * w.w;
        }
    }
#pragma unroll
    for (int w = 0; w < 32; ++w) q[w] *= c2;

    if (j == 0) {   // shortcut: (x @ Wsc) * 1/4, only the 0e path
        const float* xp = x + (n << 4);
#pragma unroll
        for (int uu = 0; uu < 16; ++uu) {
            float xv = 0.25f * xp[uu];
            const float4* w4 = (const float4*)(sSc + (uu << 5));
#pragma unroll
            for (int wd = 0; wd < 8; ++wd) {
                float4 w = w4[wd];
                q[4*wd+0] += xv * w.x;
                q[4*wd+1] += xv * w.y;
                q[4*wd+2] += xv * w.z;
                q[4*wd+3] += xv * w.w;
            }
        }
    }

    float* op = out + (n << 9) + offl + i;
#pragma unroll
    for (int w = 0; w < 32; ++w) op[w * deg] = q[w];
}

extern "C" void kernel_launch(void* const* d_in, const int* in_sizes, int n_in,
                              void* d_out, int out_size, void* d_ws, size_t ws_size,
                              hipStream_t stream) {
    const float* x     = (const float*)d_in[0];
    const float* pos   = (const float*)d_in[1];
    const float* Wpre  = (const float*)d_in[2];
    const float* Wpost = (const float*)d_in[3];
    const float* Wsc   = (const float*)d_in[4];
    const int*   snd   = (const int*)d_in[5];
    const int*   rcv   = (const int*)d_in[6];
    float* out = (float*)d_out;

    char* ws = (char*)d_ws;
    int*    cnt     = (int*)(ws);                 // 128 KiB
    int*    cur     = (int*)(ws + 0x20000);       // 128 KiB
    int*    row_ptr = (int*)(ws + 0x40000);       // 128 KiB + 4
    float4* edata   = (float4*)(ws + 0x60040);    // 16 MiB (64B aligned)

    hipMemsetAsync(ws, 0, 0x40000, stream);       // cnt + cur
    hist_k<<<EN / 1024, 256, 0, stream>>>(rcv, cnt);
    scan_k<<<1, 1024, 0, stream>>>(cnt, row_ptr);
    fill_k<<<EN / 256, 256, 0, stream>>>(snd, rcv, row_ptr, cur, pos, edata);
    fused_k<<<NN / GROUPS, BLK, 0, stream>>>(x, pos, row_ptr, edata,
                                             Wpre, Wpost, Wsc, out);
}

// Round 8
// 201.606 us; speedup vs baseline: 1.5892x; 1.3807x over previous
//
#include <hip/hip_runtime.h>
#include <math.h>

#define NN 32768
#define EN 1048576
#define NBIN 256          // coarse bins: bin = rcv >> 7 (128 receivers per bin)
#define BINCAP 8192       // slots per coarse bin (avg 4096, 64 sigma headroom)
#define TILE 4096         // edges per bin_k block

// C = 1/sqrt(E[gelu(z)^2]) , E = 1/3 + 1/(2*pi*sqrt(3))
#define C_GELU_F 1.5335262f

// ---------------- pass A: coarse-bin edges, coalesced writes ----------------
// word = (rcv << 15) | snd  (30 bits); bin = word >> 22.
__global__ __launch_bounds__(512) void bin_k(const int* __restrict__ snd,
                                             const int* __restrict__ rcv,
                                             int* __restrict__ bin_cur,
                                             unsigned* __restrict__ binbuf) {
    __shared__ unsigned cnt[NBIN];
    __shared__ unsigned excl[NBIN];
    __shared__ unsigned cur2[NBIN];
    __shared__ unsigned gbase[NBIN];
    __shared__ unsigned stage[TILE];
    int t = threadIdx.x;
    int tile = blockIdx.x * TILE;
    if (t < NBIN) { cnt[t] = 0; cur2[t] = 0; }
    __syncthreads();

    unsigned w[TILE / 512];
#pragma unroll
    for (int i = 0; i < TILE / 512; ++i) {
        int e = tile + i * 512 + t;
        unsigned r = (unsigned)rcv[e], s = (unsigned)snd[e];
        w[i] = (r << 15) | s;
        atomicAdd(&cnt[w[i] >> 22], 1u);
    }
    __syncthreads();

    unsigned my = (t < NBIN) ? cnt[t] : 0u;
    if (t < NBIN) excl[t] = my;
    __syncthreads();
    for (int d = 1; d < NBIN; d <<= 1) {
        unsigned v = (t < NBIN && t >= d) ? excl[t - d] : 0u;
        __syncthreads();
        if (t < NBIN) excl[t] += v;
        __syncthreads();
    }
    if (t < NBIN) {
        unsigned myexcl = excl[t] - my;
        gbase[t] = atomicAdd((unsigned*)&bin_cur[t], my);
        excl[t] = myexcl;
    }
    __syncthreads();

#pragma unroll
    for (int i = 0; i < TILE / 512; ++i) {
        unsigned b = w[i] >> 22;
        unsigned p = excl[b] + atomicAdd(&cur2[b], 1u);
        stage[p] = w[i];
    }
    __syncthreads();

    for (int p = t; p < TILE; p += 512) {
        unsigned ww = stage[p];
        unsigned b = ww >> 22;
        unsigned idx = gbase[b] + ((unsigned)p - excl[b]);
        if (idx < BINCAP) binbuf[b * BINCAP + idx] = ww;
    }
}

// ---------------- scan over bins -> global CSR base per bin -----------------
__global__ __launch_bounds__(256) void scan_k(const int* __restrict__ bin_cur,
                                              int* __restrict__ bin_start) {
    __shared__ unsigned sc[NBIN];
    int t = threadIdx.x;
    unsigned my = (unsigned)bin_cur[t];
    sc[t] = my;
    __syncthreads();
    for (int d = 1; d < NBIN; d <<= 1) {
        unsigned v = (t >= d) ? sc[t - d] : 0u;
        __syncthreads();
        sc[t] += v;
        __syncthreads();
    }
    bin_start[t] = (int)(sc[t] - my);
}

// ---------------- pass B: per-bin counting sort -> dense packed records ------
// Writes edata[base..base+M) = {sender_pos.xyz, sender_id} in a 64KB dense
// window (full 64B lines, zero write amplification). Bin words staged in LDS
// so the bin is fetched from HBM exactly once.
__global__ __launch_bounds__(1024) void csrfill_k(const int* __restrict__ bin_cur,
                                                  const int* __restrict__ bin_start,
                                                  const unsigned* __restrict__ binbuf,
                                                  const float* __restrict__ pos,
                                                  int* __restrict__ row_ptr,
                                                  float4* __restrict__ edata) {
    __shared__ unsigned cnt[128];
    __shared__ unsigned excl[128];
    __shared__ unsigned cur2[128];
    __shared__ unsigned words[BINCAP];   // 32 KB
    int b = blockIdx.x;
    int t = threadIdx.x;
    int M = bin_cur[b]; M = M > BINCAP ? BINCAP : M;
    int base = bin_start[b];
    if (t < 128) { cnt[t] = 0; cur2[t] = 0; }
    __syncthreads();

    const unsigned* bb = binbuf + b * BINCAP;
    for (int i = t; i < M; i += 1024) {
        unsigned ww = bb[i];
        words[i] = ww;
        atomicAdd(&cnt[(ww >> 15) & 127], 1u);
    }
    __syncthreads();

    if (t < 128) excl[t] = cnt[t];
    __syncthreads();
    for (int d = 1; d < 128; d <<= 1) {
        unsigned v = (t >= d && t < 128) ? excl[t - d] : 0u;
        __syncthreads();
        if (t < 128) excl[t] += v;
        __syncthreads();
    }
    if (t < 128) {
        unsigned e = excl[t] - cnt[t];
        excl[t] = e;
        row_ptr[(b << 7) + t] = base + (int)e;
        if (b == NBIN - 1 && t == 127) row_ptr[NN] = base + (int)(e + cnt[127]);
    }
    __syncthreads();

    for (int i = t; i < M; i += 1024) {
        unsigned ww = words[i];
        unsigned r7 = (ww >> 15) & 127;
        unsigned dst = excl[r7] + atomicAdd(&cur2[r7], 1u);
        int s = (int)(ww & 0x7FFF);
        const float* ps = pos + 3 * s;        // L2-resident (384 KB)
        edata[base + dst] = make_float4(ps[0], ps[1], ps[2], __int_as_float(s));
    }
}

// ---------------- fused aggregate + node update ------------------------------
// Per 16-lane node group, chunk of 16 edges:
//   step A: lane e computes SH for edge e (from packed record), stores
//           TRANSPOSED yT[comp][e] + sender ids into LDS (zero-masked tail).
//   step B: lane j reads row yT[j][0..15] (4x b128) + senders (4x b128
//           broadcast) -> 16 edges x (4 indep global dwordx4 + 16 FMA).
// LDS UNION: sY region reused for weight tiles after the edge loop.
// *** sU must cover BOTH uses: GROUPS*GST=5504 for sY, 6688 for weights
// (2064 sPre + 4112 sPost + 512 sSc). R7 bug: sized 5504 -> weight overflow.
#define GROUPS 16
#define BLK 256
#define GST 344            // floats/group: 16 rows x 20 + 16 senders + 8 pad
#define SU_FLOATS 6688     // max(GROUPS*GST, 2064+4112+512)

__global__ __launch_bounds__(256, 4) void fused_k(const float* __restrict__ x,
                                                  const float* __restrict__ pos,
                                                  const int* __restrict__ row_ptr,
                                                  const float4* __restrict__ edata,
                                                  const float* __restrict__ Wpre,
                                                  const float* __restrict__ Wpost,
                                                  const float* __restrict__ Wsc,
                                                  float* __restrict__ out) {
    __shared__ float sU[SU_FLOATS];      // 26752 B

    int t = threadIdx.x;
    int g = t >> 4;
    int j = t & 15;
    int n = blockIdx.x * GROUPS + g;
    int beg = row_ptr[n], end = row_ptr[n + 1];
    int cnt = end - beg;
    const float* pr = pos + 3 * n;       // L2-hit, group-broadcast
    float rpx = pr[0], rpy = pr[1], rpz = pr[2];
    float* yg = sU + g * GST;            // yT rows at m*20, senders at 320

    const float s3   = 1.7320508075688772f;
    const float s5   = 2.2360679774997896f;
    const float s15  = 3.8729833462074170f;
    const float s7   = 2.6457513110645907f;
    const float s105 = 10.246950765959598f;
    const float s35_8 = 2.0916500663351889f;
    const float s21_8 = 1.6201851746019651f;

    float acc[16];
#pragma unroll
    for (int u = 0; u < 16; ++u) acc[u] = 0.f;

    int nch = (cnt + 15) >> 4;
    for (int c = 0; c < nch; ++c) {
        // ---- step A: my edge's SH (transposed store, zero-masked tail) ----
        int k = (c << 4) + j;
        bool valid = k < cnt;
        int ki = valid ? k : cnt - 1;
        float4 rec = edata[beg + ki];
        int sE = __float_as_int(rec.w);
        float vx = rpx - rec.x, vy = rpy - rec.y, vz = rpz - rec.z;
        float n2 = vx*vx + vy*vy + vz*vz;
        float inv;
        if (valid && n2 > 0.f) {
            inv = rsqrtf(n2);
            inv = inv * (1.5f - 0.5f * n2 * inv * inv);   // Newton: ~exact f32
        } else inv = 0.f;
        float X = vx*inv, Y = vy*inv, Z = vz*inv;
        float XX = X*X, YY = Y*Y, ZZ = Z*Z;
        float zm = valid ? 1.f : 0.f;

        yg[ 0*20 + j] = zm;                              // l=0 (masked)
        yg[ 1*20 + j] = s3*X;
        yg[ 2*20 + j] = s3*Y;
        yg[ 3*20 + j] = s3*Z;
        yg[ 4*20 + j] = s15*X*Y;
        yg[ 5*20 + j] = s15*Y*Z;
        yg[ 6*20 + j] = zm * (0.5f*s5*(3.f*ZZ - 1.f));   // masked (const term)
        yg[ 7*20 + j] = s15*X*Z;
        yg[ 8*20 + j] = 0.5f*s15*(XX - YY);
        yg[ 9*20 + j] = s35_8*Y*(3.f*XX - YY);
        yg[10*20 + j] = s105*X*Y*Z;
        yg[11*20 + j] = s21_8*Y*(5.f*ZZ - 1.f);
        yg[12*20 + j] = 0.5f*s7*Z*(5.f*ZZ - 3.f);
        yg[13*20 + j] = s21_8*X*(5.f*ZZ - 1.f);
        yg[14*20 + j] = 0.5f*s105*Z*(XX - YY);
        yg[15*20 + j] = s35_8*X*(XX - 3.f*YY);
        ((int*)(yg + 320))[j] = sE;

        // ---- step B: my j-column over the chunk's 16 edges ----
        const float4* yp = (const float4*)(yg + j * 20);  // row j: y_e[j]
        float4 yv0 = yp[0], yv1 = yp[1], yv2 = yp[2], yv3 = yp[3];
        const int4* sip = (const int4*)(yg + 320);        // broadcast reads
        int4 sa0 = sip[0], sa1 = sip[1], sa2 = sip[2], sa3 = sip[3];
        float yarr[16] = { yv0.x, yv0.y, yv0.z, yv0.w,
                           yv1.x, yv1.y, yv1.z, yv1.w,
                           yv2.x, yv2.y, yv2.z, yv2.w,
                           yv3.x, yv3.y, yv3.z, yv3.w };
        int sarr[16] = { sa0.x, sa0.y, sa0.z, sa0.w,
                         sa1.x, sa1.y, sa1.z, sa1.w,
                         sa2.x, sa2.y, sa2.z, sa2.w,
                         sa3.x, sa3.y, sa3.z, sa3.w };
#pragma unroll
        for (int e = 0; e < 16; ++e) {
            float y = yarr[e];
            const float4* xp = (const float4*)(x + (sarr[e] << 4));
            float4 a0 = xp[0], a1 = xp[1], a2 = xp[2], a3 = xp[3];
            acc[0]  += a0.x * y;  acc[1]  += a0.y * y;
            acc[2]  += a0.z * y;  acc[3]  += a0.w * y;
            acc[4]  += a1.x * y;  acc[5]  += a1.y * y;
            acc[6]  += a1.z * y;  acc[7]  += a1.w * y;
            acc[8]  += a2.x * y;  acc[9]  += a2.y * y;
            acc[10] += a2.z * y;  acc[11] += a2.w * y;
            acc[12] += a3.x * y;  acc[13] += a3.y * y;
            acc[14] += a3.z * y;  acc[15] += a3.w * y;
        }
    }

    // ---- stage weights into the SAME LDS region (sY is dead now) ----
    __syncthreads();
    float* sPre  = sU;            // 4 x 516   = 2064
    float* sPost = sU + 2064;     // 4 x 1028  = 4112 (ends 6176)
    float* sSc   = sU + 6176;     // 512        (ends 6688 = SU_FLOATS)
    for (int idx = t; idx < 2048; idx += BLK)
        sPre[(idx >> 9)*516 + (idx & 511)] = Wpre[idx];
    for (int idx = t; idx < 4096; idx += BLK)
        sPost[(idx >> 10)*1028 + (idx & 1023)] = Wpost[idx];
    sSc[t] = Wsc[t];
    sSc[t + 256] = Wsc[t + 256];
    __syncthreads();

    // ---- phase 3: per-(n,j) node update; input = acc registers ----
    int l, i, offl, deg;
    if (j == 0)      { l = 0; i = 0;     offl = 0;   deg = 1; }
    else if (j < 4)  { l = 1; i = j - 1; offl = 32;  deg = 3; }
    else if (j < 9)  { l = 2; i = j - 4; offl = 128; deg = 5; }
    else             { l = 3; i = j - 9; offl = 288; deg = 7; }

    const float c1 = 0.0078125f;            // (1/DENOM) * inv_in
    const float c2 = 0.17677669529663687f;  // 1/sqrt(32)

    float p[32];
#pragma unroll
    for (int v = 0; v < 32; ++v) p[v] = 0.f;
    const float* wp = sPre + l * 516;
#pragma unroll
    for (int uu = 0; uu < 16; ++uu) {
        float a = acc[uu];
        const float4* w4 = (const float4*)(wp + (uu << 5));
#pragma unroll
        for (int vq = 0; vq < 8; ++vq) {
            float4 w = w4[vq];
            p[4*vq+0] += a * w.x;
            p[4*vq+1] += a * w.y;
            p[4*vq+2] += a * w.z;
            p[4*vq+3] += a * w.w;
        }
    }
#pragma unroll
    for (int v = 0; v < 32; ++v) p[v] *= c1;

    if (j == 0) {
#pragma unroll
        for (int v = 0; v < 32; ++v) {
            float pv = p[v];
            p[v] = C_GELU_F * 0.5f * pv * (1.f + erff(pv * 0.7071067811865476f));
        }
    }

    float q[32];
#pragma unroll
    for (int w = 0; w < 32; ++w) q[w] = 0.f;
    const float* wq = sPost + l * 1028;
#pragma unroll
    for (int v = 0; v < 32; ++v) {
        float pv = p[v];
        const float4* w4 = (const float4*)(wq + (v << 5));
#pragma unroll
        for (int wd = 0; wd < 8; ++wd) {
            float4 w = w4[wd];
            q[4*wd+0] += pv * w.x;
            q[4*wd+1] += pv * w.y;
            q[4*wd+2] += pv * w.z;
            q[4*wd+3] += pv * w.w;
        }
    }
#pragma unroll
    for (int w = 0; w < 32; ++w) q[w] *= c2;

    if (j == 0) {   // shortcut: (x @ Wsc) * 1/4, only the 0e path
        const float* xp = x + (n << 4);
#pragma unroll
        for (int uu = 0; uu < 16; ++uu) {
            float xv = 0.25f * xp[uu];
            const float4* w4 = (const float4*)(sSc + (uu << 5));
#pragma unroll
            for (int wd = 0; wd < 8; ++wd) {
                float4 w = w4[wd];
                q[4*wd+0] += xv * w.x;
                q[4*wd+1] += xv * w.y;
                q[4*wd+2] += xv * w.z;
                q[4*wd+3] += xv * w.w;
            }
        }
    }

    float* op = out + (n << 9) + offl + i;
#pragma unroll
    for (int w = 0; w < 32; ++w) op[w * deg] = q[w];
}

extern "C" void kernel_launch(void* const* d_in, const int* in_sizes, int n_in,
                              void* d_out, int out_size, void* d_ws, size_t ws_size,
                              hipStream_t stream) {
    const float* x     = (const float*)d_in[0];
    const float* pos   = (const float*)d_in[1];
    const float* Wpre  = (const float*)d_in[2];
    const float* Wpost = (const float*)d_in[3];
    const float* Wsc   = (const float*)d_in[4];
    const int*   snd   = (const int*)d_in[5];
    const int*   rcv   = (const int*)d_in[6];
    float* out = (float*)d_out;

    char* ws = (char*)d_ws;
    int*      bin_cur   = (int*)(ws);                 // 1 KiB
    int*      bin_start = (int*)(ws + 0x400);         // 1 KiB
    int*      row_ptr   = (int*)(ws + 0x800);         // 128 KiB + 4
    unsigned* binbuf    = (unsigned*)(ws + 0x40000);  // 8 MiB
    float4*   edata     = (float4*)(ws + 0x900000);   // 16 MiB (64B aligned)

    hipMemsetAsync(bin_cur, 0, NBIN * sizeof(int), stream);
    bin_k<<<EN / TILE, 512, 0, stream>>>(snd, rcv, bin_cur, binbuf);
    scan_k<<<1, 256, 0, stream>>>(bin_cur, bin_start);
    csrfill_k<<<NBIN, 1024, 0, stream>>>(bin_cur, bin_start, binbuf, pos,
                                         row_ptr, edata);
    fused_k<<<NN / GROUPS, BLK, 0, stream>>>(x, pos, row_ptr, edata,
                                             Wpre, Wpost, Wsc, out);
}